// Round 1
// baseline (497.009 us; speedup 1.0000x reference)
//
#include <hip/hip_runtime.h>
#include <math.h>

// Workspace layout (4-byte words):
#define W2OFF  0        // 8192 floats: W2[e][d] = sum_o key[e][o]*Wq[o][d]
#define B2OFF  8192     // 8 floats:    b2[e]    = sum_d bq[d]*key[e][d]
#define SCOFF  8200     // 512 floats:  score sums [batch][e]
#define AUXOFF 8712     // 1 float:     sum of w*log(w+1e-9)
#define CNTOFF 8713     // 64 ints:     per-batch block-arrival counters
#define GDOFF  8777     // 1 int:       batch-finisher arrival counter
#define ZTOT   578      // words to zero starting at SCOFF (512+1+64+1)
#define KEYP   1088     // skew-padded per-expert LDS stride for key

// ---------------- k01: W2 = key@Wq, b2 = bq.key, zero accumulators ----------------
// 128 blocks x 256 thr; block owns 8 output columns d; 32 o-groups of 32.
// keyl skew layout word(e,o) = e*KEYP + o + (o>>5): the inner-loop read
// keyl[e*KEYP + og*33 + oo] puts the wave's 8 og values on 8 distinct banks
// (og*33 % 32 = og) instead of the 8-way conflict of the linear layout.
__global__ __launch_bounds__(256) void k01_prep(const float* __restrict__ Wq,
                                                const float* __restrict__ key,
                                                const float* __restrict__ bq,
                                                float* __restrict__ ws) {
    __shared__ __attribute__((aligned(16))) float keyl[8 * KEYP];  // 34 KB
    __shared__ float part[256 * 8];                                // 8 KB
    __shared__ float part2[64];
    int tid = threadIdx.x;
    int blk = blockIdx.x;

    // distributed zeroing: 128 blocks x 5 words covers 578
    if (tid < 5) {
        int i = blk * 5 + tid;
        if (i < ZTOT) ws[SCOFF + i] = 0.0f;
    }

    // stage key with skew (scalar stores; global reads stay coalesced)
    #pragma unroll
    for (int k = 0; k < 32; ++k) {
        int idx = tid + 256 * k;         // 0..8191
        int e = idx >> 10, o = idx & 1023;
        keyl[e * KEYP + o + (o >> 5)] = key[idx];
    }
    __syncthreads();

    int dl = tid & 7;
    int og = tid >> 3;                   // 0..31
    int d  = blk * 8 + dl;
    int kob = og * 33;                   // og*32 + skew(og)
    float acc[8];
    #pragma unroll
    for (int e = 0; e < 8; ++e) acc[e] = 0.0f;
    #pragma unroll
    for (int oo = 0; oo < 32; ++oo) {    // full unroll: 32 Wq loads in flight
        int o = og * 32 + oo;
        float wv = Wq[o * 1024 + d];
        #pragma unroll
        for (int e = 0; e < 8; ++e) acc[e] += keyl[e * KEYP + kob + oo] * wv;
    }
    #pragma unroll
    for (int e = 0; e < 8; ++e) part[tid * 8 + e] = acc[e];
    __syncthreads();
    if (tid < 64) {
        int d2 = tid >> 3, e = tid & 7;
        float s = 0.0f;
        #pragma unroll
        for (int g = 0; g < 32; ++g) s += part[(g * 8 + d2) * 8 + e];
        ws[W2OFF + e * 1024 + blk * 8 + d2] = s;
    }

    // block 0 additionally computes b2 using the LDS-staged key (tree reduce)
    if (blk == 0) {
        __syncthreads();
        float p[8];
        #pragma unroll
        for (int e = 0; e < 8; ++e) p[e] = 0.0f;
        #pragma unroll
        for (int k = 0; k < 4; ++k) {
            int d2 = tid + 256 * k;
            float bv = bq[d2];
            int kd = d2 + (d2 >> 5);
            #pragma unroll
            for (int e = 0; e < 8; ++e) p[e] += bv * keyl[e * KEYP + kd];
        }
        #pragma unroll
        for (int e = 0; e < 8; ++e) part[tid * 8 + e] = p[e];
        __syncthreads();
        if (tid < 64) {                 // stage 1: 64 threads sum 32 rows each
            int e = tid & 7, g = tid >> 3;
            float s = 0.0f;
            #pragma unroll
            for (int k = 0; k < 32; ++k) s += part[(g * 32 + k) * 8 + e];
            part2[g * 8 + e] = s;
        }
        __syncthreads();
        if (tid < 8) {                  // stage 2: 8 threads sum 8 partials
            float s = 0.0f;
            #pragma unroll
            for (int g = 0; g < 8; ++g) s += part2[g * 8 + tid];
            ws[B2OFF + tid] = s;
        }
    }
}

__device__ __forceinline__ void top2_of8(const float* v, int& i1, int& i2) {
    i1 = 0; float b1 = v[0];
    #pragma unroll
    for (int e = 1; e < 8; ++e) if (v[e] > b1) { b1 = v[e]; i1 = e; }
    i2 = -1; float b2 = -3.4e38f;
    #pragma unroll
    for (int e = 0; e < 8; ++e) if (e != i1 && v[e] > b2) { b2 = v[e]; i2 = e; }
}

// ---------------- k2: stream x -> scores -> softmax/sums -> fused finisher ----------------
// 1024 blocks x 256 thr; block = 64 consecutive tokens of one batch.
// Tail: per-batch atomic arrival counter; 16th block of a batch reads the
// batch's final score sums coherently (atomicAdd(p,0)), computes top-2, writes
// the batch's mask + indices. The 64th batch-finisher computes the loss.
__global__ __launch_bounds__(256) void k2_main(const float* __restrict__ x,
                                               float* __restrict__ ws,
                                               float* __restrict__ out) {
    __shared__ __attribute__((aligned(16))) float w2l[8 * 1024];    // 32 KB
    __shared__ __attribute__((aligned(16))) float part[4 * 64 * 8]; // 8 KB per-wave [8][64]
    __shared__ __attribute__((aligned(16))) float sraw[64 * 8];     // 2 KB raw scores
    __shared__ float sc8[8];
    __shared__ int cnt8[8];
    __shared__ int s_flag;

    int tid  = threadIdx.x;
    int blk  = blockIdx.x;
    int lane = tid & 63;
    int w    = tid >> 6;
    int batch = blk >> 4;
    int tb    = blk * 64;
    int e = lane >> 3;      // expert owned after transpose
    int r = lane & 7;       // reduction slice -> cheap shfl masks 1/2/4

    float4* wl4 = (float4*)w2l;
    const float4* wg4 = (const float4*)(ws + W2OFF);
    #pragma unroll
    for (int k = 0; k < 8; ++k) wl4[tid + 256 * k] = wg4[tid + 256 * k];
    __syncthreads();

    const float4* x4 = (const float4*)x;
    float* pw = part + w * 512;

    for (int p = 0; p < 4; ++p) {
        int lt0 = w * 16 + p * 4;
        int t0  = tb + lt0;
        float acc[4][8];
        #pragma unroll
        for (int j = 0; j < 4; ++j)
            #pragma unroll
            for (int c = 0; c < 8; ++c) acc[j][c] = 0.0f;

        #pragma unroll
        for (int i = 0; i < 4; ++i) {
            float4 xr[4];
            #pragma unroll
            for (int j = 0; j < 4; ++j)
                xr[j] = x4[(size_t)(t0 + j) * 256 + i * 64 + lane];
            #pragma unroll
            for (int c = 0; c < 8; ++c) {
                float4 w4 = wl4[c * 256 + i * 64 + lane];
                #pragma unroll
                for (int j = 0; j < 4; ++j)
                    acc[j][c] += w4.x * xr[j].x + w4.y * xr[j].y +
                                 w4.z * xr[j].z + w4.w * xr[j].w;
            }
        }

        #pragma unroll
        for (int j = 0; j < 4; ++j) {
            // swizzled wave-internal transpose: <=2-way bank alias on write & read
            #pragma unroll
            for (int c = 0; c < 8; ++c)
                pw[c * 64 + (lane ^ (c << 3))] = acc[j][c];
            float s = 0.0f;
            #pragma unroll
            for (int m = 0; m < 8; ++m)
                s += pw[e * 64 + ((r + 8 * m) ^ (e << 3))];
            s += __shfl_xor(s, 1);
            s += __shfl_xor(s, 2);
            s += __shfl_xor(s, 4);
            if (r == 0) sraw[(lt0 + j) * 8 + e] = s;  // raw dot, pre-bias/scale
        }
    }
    __syncthreads();

    // Phase B: 64 threads, one token each, lane-local softmax
    if (tid < 64) {
        int t = tid;
        float sv[8];
        #pragma unroll
        for (int k = 0; k < 8; ++k) {        // rotated reads to spread banks
            int c = (t + k) & 7;
            sv[c] = sraw[t * 8 + c];
        }
        const float scale = 0.03125f;        // 1024^-0.5
        #pragma unroll
        for (int c = 0; c < 8; ++c) sv[c] = (sv[c] + ws[B2OFF + c]) * scale;
        float mx = sv[0];
        #pragma unroll
        for (int c = 1; c < 8; ++c) mx = fmaxf(mx, sv[c]);
        float wgt[8], sm = 0.0f;
        #pragma unroll
        for (int c = 0; c < 8; ++c) { wgt[c] = expf(sv[c] - mx); sm += wgt[c]; }
        float inv = 1.0f / sm;
        float aux = 0.0f;
        #pragma unroll
        for (int c = 0; c < 8; ++c) {
            wgt[c] *= inv;
            aux += wgt[c] * logf(wgt[c] + 1e-9f);
        }
        #pragma unroll
        for (int c = 0; c < 8; ++c)
            part[c * 64 + (t ^ (c << 3))] = wgt[c];
        int e2 = t >> 3, r2 = t & 7;
        float s2 = 0.0f;
        #pragma unroll
        for (int m = 0; m < 8; ++m)
            s2 += part[e2 * 64 + ((r2 + 8 * m) ^ (e2 << 3))];
        s2 += __shfl_xor(s2, 1);
        s2 += __shfl_xor(s2, 2);
        s2 += __shfl_xor(s2, 4);
        if (r2 == 0) atomicAdd(&ws[SCOFF + batch * 8 + e2], s2);
        #pragma unroll
        for (int mk = 1; mk <= 32; mk <<= 1) aux += __shfl_xor(aux, mk);
        if (t == 0) atomicAdd(&ws[AUXOFF], aux);
    }

    // ---- fused finisher (was k3) ----
    int* wsi = (int*)ws;
    __syncthreads();                      // barrier drains this block's atomics
    if (tid == 0) {
        __threadfence();
        int prev = atomicAdd(&wsi[CNTOFF + batch], 1);
        s_flag = (prev == 15) ? 1 : 0;
    }
    __syncthreads();
    if (s_flag) {
        __threadfence();
        // coherent read of this batch's final score sums
        if (tid < 8) sc8[tid] = atomicAdd(&ws[SCOFF + batch * 8 + tid], 0.0f);
        __syncthreads();
        float v[8];
        #pragma unroll
        for (int c = 0; c < 8; ++c) v[c] = sc8[c];
        int i1, i2;
        top2_of8(v, i1, i2);
        float m[8];
        #pragma unroll
        for (int c = 0; c < 8; ++c) m[c] = (c == i1 || c == i2) ? 1.0f : 0.0f;
        float4 mA = make_float4(m[0], m[1], m[2], m[3]);
        float4 mB = make_float4(m[4], m[5], m[6], m[7]);
        float4* o4 = (float4*)out;
        int tb0 = batch << 10;
        #pragma unroll
        for (int t = tid; t < 1024; t += 256) {
            o4[(size_t)(tb0 + t) * 2]     = mA;
            o4[(size_t)(tb0 + t) * 2 + 1] = mB;
        }
        if (tid == 0) {
            out[524288 + batch * 2]     = (float)i1;
            out[524288 + batch * 2 + 1] = (float)i2;
            __threadfence();
            int p2 = atomicAdd(&wsi[GDOFF], 1);
            s_flag = (p2 == 63) ? 2 : 0;
        }
        __syncthreads();
        if (s_flag == 2) {                // last batch-finisher: loss
            if (tid < 8) cnt8[tid] = 0;
            __syncthreads();
            if (tid < 64) {
                float vv[8];
                #pragma unroll
                for (int c = 0; c < 8; ++c)
                    vv[c] = atomicAdd(&ws[SCOFF + tid * 8 + c], 0.0f);
                int j1, j2;
                top2_of8(vv, j1, j2);
                atomicAdd(&cnt8[j1], 1);
                atomicAdd(&cnt8[j2], 1);
            }
            __syncthreads();
            if (tid == 0) {
                float kl = 0.0f;
                #pragma unroll
                for (int c = 0; c < 8; ++c) {
                    float usage = (float)cnt8[c] / 64.0f;
                    kl += 0.125f * (logf(0.125f) - logf(usage));
                }
                kl *= 0.125f;             // / E (batchmean)
                float auxv = atomicAdd(&ws[AUXOFF], 0.0f);
                out[524416] = 1e-3f * kl + 1e-3f * (auxv / 524288.0f);
            }
        }
    }
}

extern "C" void kernel_launch(void* const* d_in, const int* in_sizes, int n_in,
                              void* d_out, int out_size, void* d_ws, size_t ws_size,
                              hipStream_t stream) {
    const float* x   = (const float*)d_in[0];
    const float* Wq  = (const float*)d_in[1];
    const float* bq  = (const float*)d_in[2];
    const float* key = (const float*)d_in[3];
    float* out = (float*)d_out;
    float* ws  = (float*)d_ws;

    k01_prep<<<128,  256, 0, stream>>>(Wq, key, bq, ws);
    k2_main <<<1024, 256, 0, stream>>>(x, ws, out);
}

// Round 2
// 381.117 us; speedup vs baseline: 1.3041x; 1.3041x over previous
//
#include <hip/hip_runtime.h>
#include <math.h>

// Workspace layout (4-byte words):
#define W2OFF  0        // 8192 floats: W2[e][d] = sum_o key[e][o]*Wq[o][d]
#define B2OFF  8192     // 8 floats:    b2[e]    = sum_d bq[d]*key[e][d]
#define SCOFF  8200     // 512 floats:  score sums [batch][e]
#define AUXOFF 8712     // 1 float:     sum of w*log(w+1e-9)
#define CNTOFF 8713     // 64 ints:     per-batch block-arrival counters
#define GDOFF  8777     // 1 int:       batch-finisher arrival counter
#define ZTOT   578      // words to zero starting at SCOFF (512+1+64+1)
#define KEYP   1088     // skew-padded per-expert LDS stride for key

// ---------------- k01: W2 = key@Wq, b2 = bq.key, zero accumulators ----------------
// 128 blocks x 256 thr; block owns 8 output columns d; 32 o-groups of 32.
// keyl skew layout word(e,o) = e*KEYP + o + (o>>5): the inner-loop read
// keyl[e*KEYP + og*33 + oo] puts the wave's 8 og values on 8 distinct banks
// (og*33 % 32 = og) instead of the 8-way conflict of the linear layout.
__global__ __launch_bounds__(256) void k01_prep(const float* __restrict__ Wq,
                                                const float* __restrict__ key,
                                                const float* __restrict__ bq,
                                                float* __restrict__ ws) {
    __shared__ __attribute__((aligned(16))) float keyl[8 * KEYP];  // 34 KB
    __shared__ float part[256 * 8];                                // 8 KB
    __shared__ float part2[64];
    int tid = threadIdx.x;
    int blk = blockIdx.x;

    // distributed zeroing: 128 blocks x 5 words covers 578
    if (tid < 5) {
        int i = blk * 5 + tid;
        if (i < ZTOT) ws[SCOFF + i] = 0.0f;
    }

    // stage key with skew (scalar stores; global reads stay coalesced)
    #pragma unroll
    for (int k = 0; k < 32; ++k) {
        int idx = tid + 256 * k;         // 0..8191
        int e = idx >> 10, o = idx & 1023;
        keyl[e * KEYP + o + (o >> 5)] = key[idx];
    }
    __syncthreads();

    int dl = tid & 7;
    int og = tid >> 3;                   // 0..31
    int d  = blk * 8 + dl;
    int kob = og * 33;                   // og*32 + skew(og)
    float acc[8];
    #pragma unroll
    for (int e = 0; e < 8; ++e) acc[e] = 0.0f;
    #pragma unroll
    for (int oo = 0; oo < 32; ++oo) {    // full unroll: 32 Wq loads in flight
        int o = og * 32 + oo;
        float wv = Wq[o * 1024 + d];
        #pragma unroll
        for (int e = 0; e < 8; ++e) acc[e] += keyl[e * KEYP + kob + oo] * wv;
    }
    #pragma unroll
    for (int e = 0; e < 8; ++e) part[tid * 8 + e] = acc[e];
    __syncthreads();
    if (tid < 64) {
        int d2 = tid >> 3, e = tid & 7;
        float s = 0.0f;
        #pragma unroll
        for (int g = 0; g < 32; ++g) s += part[(g * 8 + d2) * 8 + e];
        ws[W2OFF + e * 1024 + blk * 8 + d2] = s;
    }

    // block 0 additionally computes b2 using the LDS-staged key (tree reduce)
    if (blk == 0) {
        __syncthreads();
        float p[8];
        #pragma unroll
        for (int e = 0; e < 8; ++e) p[e] = 0.0f;
        #pragma unroll
        for (int k = 0; k < 4; ++k) {
            int d2 = tid + 256 * k;
            float bv = bq[d2];
            int kd = d2 + (d2 >> 5);
            #pragma unroll
            for (int e = 0; e < 8; ++e) p[e] += bv * keyl[e * KEYP + kd];
        }
        #pragma unroll
        for (int e = 0; e < 8; ++e) part[tid * 8 + e] = p[e];
        __syncthreads();
        if (tid < 64) {                 // stage 1: 64 threads sum 32 rows each
            int e = tid & 7, g = tid >> 3;
            float s = 0.0f;
            #pragma unroll
            for (int k = 0; k < 32; ++k) s += part[(g * 32 + k) * 8 + e];
            part2[g * 8 + e] = s;
        }
        __syncthreads();
        if (tid < 8) {                  // stage 2: 8 threads sum 8 partials
            float s = 0.0f;
            #pragma unroll
            for (int g = 0; g < 8; ++g) s += part2[g * 8 + tid];
            ws[B2OFF + tid] = s;
        }
    }
}

__device__ __forceinline__ void top2_of8(const float* v, int& i1, int& i2) {
    i1 = 0; float b1 = v[0];
    #pragma unroll
    for (int e = 1; e < 8; ++e) if (v[e] > b1) { b1 = v[e]; i1 = e; }
    i2 = -1; float b2 = -3.4e38f;
    #pragma unroll
    for (int e = 0; e < 8; ++e) if (e != i1 && v[e] > b2) { b2 = v[e]; i2 = e; }
}

// ---------------- k2: stream x -> scores -> softmax/sums -> fused finisher ----------------
// 1024 blocks x 256 thr; block = 64 consecutive tokens of one batch.
// Cross-block communication is ATOMICS-ONLY (device coherence point) -> no
// __threadfence() anywhere. A per-block threadfence (buffer_wbl2+buffer_inv,
// the XCD-L2 invalidate) was measured to cost 5x on this kernel (r1: 250us
// warm-replay with ~0 HBM traffic). Ordering "my score atomics complete
// before my counter atomic" comes from the s_waitcnt vmcnt(0) the compiler
// emits for __syncthreads, plus an explicit vmcnt(0) drain.
__global__ __launch_bounds__(256) void k2_main(const float* __restrict__ x,
                                               float* __restrict__ ws,
                                               float* __restrict__ out) {
    __shared__ __attribute__((aligned(16))) float w2l[8 * 1024];    // 32 KB
    __shared__ __attribute__((aligned(16))) float part[4 * 64 * 8]; // 8 KB per-wave [8][64]
    __shared__ __attribute__((aligned(16))) float sraw[64 * 8];     // 2 KB raw scores
    __shared__ float sc8[8];
    __shared__ int cnt8[8];
    __shared__ int s_flag;

    int tid  = threadIdx.x;
    int blk  = blockIdx.x;
    int lane = tid & 63;
    int w    = tid >> 6;
    int batch = blk >> 4;
    int tb    = blk * 64;
    int e = lane >> 3;      // expert owned after transpose
    int r = lane & 7;       // reduction slice -> cheap shfl masks 1/2/4

    float4* wl4 = (float4*)w2l;
    const float4* wg4 = (const float4*)(ws + W2OFF);
    #pragma unroll
    for (int k = 0; k < 8; ++k) wl4[tid + 256 * k] = wg4[tid + 256 * k];
    __syncthreads();

    const float4* x4 = (const float4*)x;
    float* pw = part + w * 512;

    for (int p = 0; p < 4; ++p) {
        int lt0 = w * 16 + p * 4;
        int t0  = tb + lt0;
        float acc[4][8];
        #pragma unroll
        for (int j = 0; j < 4; ++j)
            #pragma unroll
            for (int c = 0; c < 8; ++c) acc[j][c] = 0.0f;

        #pragma unroll
        for (int i = 0; i < 4; ++i) {
            float4 xr[4];
            #pragma unroll
            for (int j = 0; j < 4; ++j)
                xr[j] = x4[(size_t)(t0 + j) * 256 + i * 64 + lane];
            #pragma unroll
            for (int c = 0; c < 8; ++c) {
                float4 w4 = wl4[c * 256 + i * 64 + lane];
                #pragma unroll
                for (int j = 0; j < 4; ++j)
                    acc[j][c] += w4.x * xr[j].x + w4.y * xr[j].y +
                                 w4.z * xr[j].z + w4.w * xr[j].w;
            }
        }

        #pragma unroll
        for (int j = 0; j < 4; ++j) {
            // swizzled wave-internal transpose: <=2-way bank alias on write & read
            #pragma unroll
            for (int c = 0; c < 8; ++c)
                pw[c * 64 + (lane ^ (c << 3))] = acc[j][c];
            float s = 0.0f;
            #pragma unroll
            for (int m = 0; m < 8; ++m)
                s += pw[e * 64 + ((r + 8 * m) ^ (e << 3))];
            s += __shfl_xor(s, 1);
            s += __shfl_xor(s, 2);
            s += __shfl_xor(s, 4);
            if (r == 0) sraw[(lt0 + j) * 8 + e] = s;  // raw dot, pre-bias/scale
        }
    }
    __syncthreads();

    // Phase B: 64 threads, one token each, lane-local softmax
    if (tid < 64) {
        int t = tid;
        float sv[8];
        #pragma unroll
        for (int k = 0; k < 8; ++k) {        // rotated reads to spread banks
            int c = (t + k) & 7;
            sv[c] = sraw[t * 8 + c];
        }
        const float scale = 0.03125f;        // 1024^-0.5
        #pragma unroll
        for (int c = 0; c < 8; ++c) sv[c] = (sv[c] + ws[B2OFF + c]) * scale;
        float mx = sv[0];
        #pragma unroll
        for (int c = 1; c < 8; ++c) mx = fmaxf(mx, sv[c]);
        float wgt[8], sm = 0.0f;
        #pragma unroll
        for (int c = 0; c < 8; ++c) { wgt[c] = expf(sv[c] - mx); sm += wgt[c]; }
        float inv = 1.0f / sm;
        float aux = 0.0f;
        #pragma unroll
        for (int c = 0; c < 8; ++c) {
            wgt[c] *= inv;
            aux += wgt[c] * logf(wgt[c] + 1e-9f);
        }
        #pragma unroll
        for (int c = 0; c < 8; ++c)
            part[c * 64 + (t ^ (c << 3))] = wgt[c];
        int e2 = t >> 3, r2 = t & 7;
        float s2 = 0.0f;
        #pragma unroll
        for (int m = 0; m < 8; ++m)
            s2 += part[e2 * 64 + ((r2 + 8 * m) ^ (e2 << 3))];
        s2 += __shfl_xor(s2, 1);
        s2 += __shfl_xor(s2, 2);
        s2 += __shfl_xor(s2, 4);
        if (r2 == 0) atomicAdd(&ws[SCOFF + batch * 8 + e2], s2);
        #pragma unroll
        for (int mk = 1; mk <= 32; mk <<= 1) aux += __shfl_xor(aux, mk);
        if (t == 0) atomicAdd(&ws[AUXOFF], aux);
    }

    // ---- fused finisher (was k3); atomics-only, NO threadfence ----
    int* wsi = (int*)ws;
    __syncthreads();   // compiler emits s_waitcnt vmcnt(0): score/aux atomics complete
    if (tid == 0) {
        asm volatile("s_waitcnt vmcnt(0)" ::: "memory");
        int prev = atomicAdd(&wsi[CNTOFF + batch], 1);
        s_flag = (prev == 15) ? 1 : 0;
    }
    __syncthreads();
    if (s_flag) {
        // coherent read of this batch's final score sums via atomic RMW
        if (tid < 8) sc8[tid] = atomicAdd(&ws[SCOFF + batch * 8 + tid], 0.0f);
        __syncthreads();
        float v[8];
        #pragma unroll
        for (int c = 0; c < 8; ++c) v[c] = sc8[c];
        int i1, i2;
        top2_of8(v, i1, i2);
        float m[8];
        #pragma unroll
        for (int c = 0; c < 8; ++c) m[c] = (c == i1 || c == i2) ? 1.0f : 0.0f;
        float4 mA = make_float4(m[0], m[1], m[2], m[3]);
        float4 mB = make_float4(m[4], m[5], m[6], m[7]);
        float4* o4 = (float4*)out;
        int tb0 = batch << 10;
        #pragma unroll
        for (int t = tid; t < 1024; t += 256) {
            o4[(size_t)(tb0 + t) * 2]     = mA;
            o4[(size_t)(tb0 + t) * 2 + 1] = mB;
        }
        if (tid == 0) {
            out[524288 + batch * 2]     = (float)i1;
            out[524288 + batch * 2 + 1] = (float)i2;
            // only the GDOFF ordering needs the score atomics (already done);
            // out-writes are host-visible at kernel-end implicit release.
            asm volatile("s_waitcnt vmcnt(0)" ::: "memory");
            int p2 = atomicAdd(&wsi[GDOFF], 1);
            s_flag = (p2 == 63) ? 2 : 0;
        }
        __syncthreads();
        if (s_flag == 2) {                // last batch-finisher: loss
            if (tid < 8) cnt8[tid] = 0;
            __syncthreads();
            if (tid < 64) {
                float vv[8];
                #pragma unroll
                for (int c = 0; c < 8; ++c)
                    vv[c] = atomicAdd(&ws[SCOFF + tid * 8 + c], 0.0f);
                int j1, j2;
                top2_of8(vv, j1, j2);
                atomicAdd(&cnt8[j1], 1);
                atomicAdd(&cnt8[j2], 1);
            }
            __syncthreads();
            if (tid == 0) {
                float kl = 0.0f;
                #pragma unroll
                for (int c = 0; c < 8; ++c) {
                    float usage = (float)cnt8[c] / 64.0f;
                    kl += 0.125f * (logf(0.125f) - logf(usage));
                }
                kl *= 0.125f;             // / E (batchmean)
                float auxv = atomicAdd(&ws[AUXOFF], 0.0f);
                out[524416] = 1e-3f * kl + 1e-3f * (auxv / 524288.0f);
            }
        }
    }
}

extern "C" void kernel_launch(void* const* d_in, const int* in_sizes, int n_in,
                              void* d_out, int out_size, void* d_ws, size_t ws_size,
                              hipStream_t stream) {
    const float* x   = (const float*)d_in[0];
    const float* Wq  = (const float*)d_in[1];
    const float* bq  = (const float*)d_in[2];
    const float* key = (const float*)d_in[3];
    float* out = (float*)d_out;
    float* ws  = (float*)d_ws;

    k01_prep<<<128,  256, 0, stream>>>(Wq, key, bq, ws);
    k2_main <<<1024, 256, 0, stream>>>(x, ws, out);
}